// Round 1
// baseline (458.606 us; speedup 1.0000x reference)
//
#include <hip/hip_runtime.h>

// Problem constants (from reference setup_inputs / FILTER_SIZE=3)
#define B_ 4
#define C_ 3
#define H_ 384
#define W_ 1248
#define F_ 3
#define KK_ 9               // F*F
#define W4_ (W_ / 4)        // 312

constexpr int N_FEAT = B_ * KK_ * C_ * H_ * W_;   // 51,757,056 per tensor
constexpr int N4     = N_FEAT / 4;                // 12,939,264 float4 per tensor

// One thread per output float4. Stores are 16B-aligned and fully coalesced.
// Input reads: aligned float4 when dx==0, else 4 scalar loads (cache-served).
__global__ __launch_bounds__(256) void unfold_kernel(
    const float* __restrict__ left,
    const float* __restrict__ right,
    float* __restrict__ out)
{
    int idx = blockIdx.x * blockDim.x + threadIdx.x;
    const int total = 2 * N4;
    if (idx >= total) return;

    const float* in = left;
    float* o = out;
    int t = idx;
    if (t >= N4) { t -= N4; in = right; o = out + N_FEAT; }

    // Decompose t -> (b, k, c, y, x4). Output channel = k*C + c.
    int x4 = t % W4_;
    int r  = t / W4_;
    int y  = r % H_;
    int r2 = r / H_;
    int c  = r2 % C_;
    int r3 = r2 / C_;
    int k  = r3 % KK_;
    int b  = r3 / KK_;

    int dy = k / F_ - 1;
    int dx = k % F_ - 1;
    int yin = y + dy;

    float4 v = make_float4(0.f, 0.f, 0.f, 0.f);
    if (yin >= 0 && yin < H_) {
        const float* row = in + ((size_t)((b * C_ + c) * H_ + yin)) * W_;
        int x0 = x4 * 4;
        if (dx == 0) {
            v = *reinterpret_cast<const float4*>(row + x0);
        } else {
            float tmp[4];
            #pragma unroll
            for (int j = 0; j < 4; ++j) {
                int xin = x0 + j + dx;
                tmp[j] = (xin >= 0 && xin < W_) ? row[xin] : 0.f;
            }
            v = make_float4(tmp[0], tmp[1], tmp[2], tmp[3]);
        }
    }
    *reinterpret_cast<float4*>(o + (size_t)t * 4) = v;
}

// one_hot_filter = eye(9).reshape(9,1,1,3,3): flat[i] = (i % 10 == 0) ? 1 : 0
__global__ void onehot_kernel(float* __restrict__ out)
{
    int i = threadIdx.x;
    if (i < KK_ * KK_) out[i] = (i % 10 == 0) ? 1.0f : 0.0f;
}

extern "C" void kernel_launch(void* const* d_in, const int* in_sizes, int n_in,
                              void* d_out, int out_size, void* d_ws, size_t ws_size,
                              hipStream_t stream)
{
    const float* left  = (const float*)d_in[0];
    const float* right = (const float*)d_in[1];
    float* out = (float*)d_out;

    const int total4 = 2 * N4;
    int blocks = (total4 + 255) / 256;
    unfold_kernel<<<blocks, 256, 0, stream>>>(left, right, out);
    onehot_kernel<<<1, 128, 0, stream>>>(out + (size_t)2 * N_FEAT);
}

// Round 2
// 443.693 us; speedup vs baseline: 1.0336x; 1.0336x over previous
//
#include <hip/hip_runtime.h>

// Problem constants (reference: B=4, C=3, H=384, W=1248, FILTER_SIZE=3)
#define B_ 4
#define C_ 3
#define H_ 384
#define W_ 1248
#define F_ 3
#define KK_ 9               // F*F
#define W4_ (W_ / 4)        // 312

constexpr int N_FEAT = B_ * KK_ * C_ * H_ * W_;   // 51,757,056 per tensor
constexpr int NTH    = B_ * C_ * H_ * W4_;        // 1,437,696 threads

// One thread per (b, c, y, x4). Loads 3 input rows (aligned float4 + 2 edge
// scalars) for BOTH tensors, then emits all 9 shifted outputs each: 18
// coalesced float4 stores per thread. Index math amortized 18x vs v1.
__global__ __launch_bounds__(256) void unfold9_kernel(
    const float* __restrict__ left,
    const float* __restrict__ right,
    float* __restrict__ out)
{
    int t = blockIdx.x * blockDim.x + threadIdx.x;
    if (t >= NTH) return;

    int x4 = t % W4_;
    int r  = t / W4_;
    int y  = r % H_;
    int r2 = r / H_;
    int c  = r2 % C_;
    int b  = r2 / C_;
    int x0 = x4 * 4;

    const size_t inbase = ((size_t)(b * C_ + c)) * H_ * W_;
    const float* ins[2] = { left, right };

    float4 m[2][3];
    float  lf[2][3], rg[2][3];

    #pragma unroll
    for (int s = 0; s < 2; ++s) {
        #pragma unroll
        for (int dy = 0; dy < 3; ++dy) {
            int yin = y + dy - 1;
            if (yin >= 0 && yin < H_) {
                const float* rp = ins[s] + inbase + (size_t)yin * W_;
                m[s][dy]  = *reinterpret_cast<const float4*>(rp + x0);
                lf[s][dy] = (x0 > 0)        ? rp[x0 - 1] : 0.f;
                rg[s][dy] = (x0 + 4 < W_)   ? rp[x0 + 4] : 0.f;
            } else {
                m[s][dy]  = make_float4(0.f, 0.f, 0.f, 0.f);
                lf[s][dy] = 0.f;
                rg[s][dy] = 0.f;
            }
        }
    }

    // out[b, k*C+c, y, x]: base offset for k, then +C_*H_*W_ per k step
    const size_t row_off = (((size_t)(b * KK_) * C_ + c) * H_ + y) * W_ + x0;
    const size_t kstride = (size_t)C_ * H_ * W_;

    #pragma unroll
    for (int s = 0; s < 2; ++s) {
        float* ob = out + (size_t)s * N_FEAT + row_off;
        #pragma unroll
        for (int dy = 0; dy < 3; ++dy) {
            float4 mm = m[s][dy];
            float4 vL = make_float4(lf[s][dy], mm.x, mm.y, mm.z); // dx=-1
            float4 vR = make_float4(mm.y, mm.z, mm.w, rg[s][dy]); // dx=+1
            *reinterpret_cast<float4*>(ob + (size_t)(dy * 3 + 0) * kstride) = vL;
            *reinterpret_cast<float4*>(ob + (size_t)(dy * 3 + 1) * kstride) = mm;
            *reinterpret_cast<float4*>(ob + (size_t)(dy * 3 + 2) * kstride) = vR;
        }
    }
}

// one_hot_filter = eye(9).reshape(9,1,1,3,3): flat[i] = (i % 10 == 0)
__global__ void onehot_kernel(float* __restrict__ out)
{
    int i = threadIdx.x;
    if (i < KK_ * KK_) out[i] = (i % 10 == 0) ? 1.0f : 0.0f;
}

extern "C" void kernel_launch(void* const* d_in, const int* in_sizes, int n_in,
                              void* d_out, int out_size, void* d_ws, size_t ws_size,
                              hipStream_t stream)
{
    const float* left  = (const float*)d_in[0];
    const float* right = (const float*)d_in[1];
    float* out = (float*)d_out;

    int blocks = (NTH + 255) / 256;
    unfold9_kernel<<<blocks, 256, 0, stream>>>(left, right, out);
    onehot_kernel<<<1, 128, 0, stream>>>(out + (size_t)2 * N_FEAT);
}